// Round 3
// baseline (1474.776 us; speedup 1.0000x reference)
//
#include <hip/hip_runtime.h>
#include <hip/hip_bf16.h>

#define NN 100000
#define EE 1600000
#define INC 256
#define OUTC 128
#define NBUK 782            // ceil(100000 / 128) node buckets
#define NPB  256            // partition blocks
#define CHUNK ((EE + NPB - 1) / NPB)   // 6250 edges per partition block

typedef short bf16x8 __attribute__((ext_vector_type(8)));
typedef float f32x4 __attribute__((ext_vector_type(4)));

static __device__ __forceinline__ unsigned short f2bf(float f){
    unsigned u = __builtin_bit_cast(unsigned, f);
    u += 0x7fffu + ((u >> 16) & 1u);
    return (unsigned short)(u >> 16);
}
static __device__ __forceinline__ float bf2f(unsigned u16){
    unsigned u = u16 << 16;
    return __builtin_bit_cast(float, u);
}

// ---------- bucket histogram (LDS-aggregated) ----------
__global__ void hist_kernel(const int* __restrict__ col, unsigned* __restrict__ bcnt){
    __shared__ unsigned h[NBUK];
    for (int i = threadIdx.x; i < NBUK; i += 256) h[i] = 0;
    __syncthreads();
    for (int i = blockIdx.x*blockDim.x + threadIdx.x; i < EE; i += gridDim.x*blockDim.x)
        atomicAdd(&h[((unsigned)col[i]) >> 7], 1u);
    __syncthreads();
    for (int i = threadIdx.x; i < NBUK; i += 256)
        if (h[i]) atomicAdd(&bcnt[i], h[i]);
}

// ---------- scan of 782 bucket counts -> base, cursor ----------
__global__ void scanb_kernel(const unsigned* __restrict__ bcnt,
                             unsigned* __restrict__ base, unsigned* __restrict__ cursor){
    __shared__ unsigned tmp[1024];
    int t = threadIdx.x;
    unsigned v = (t < NBUK) ? bcnt[t] : 0u;
    tmp[t] = v;
    __syncthreads();
    for (int off = 1; off < 1024; off <<= 1){
        unsigned x = (t >= off) ? tmp[t-off] : 0u;
        __syncthreads();
        tmp[t] += x;
        __syncthreads();
    }
    if (t < NBUK){ unsigned ex = tmp[t] - v; base[t] = ex; cursor[t] = ex; }
    if (t == 0) base[NBUK] = EE;
}

// ---------- partition edges into bucket regions (block-batched reservations) ----------
__global__ void partition_kernel(const int* __restrict__ ei, unsigned* __restrict__ cursor,
                                 unsigned* __restrict__ packed){
    __shared__ unsigned cnt[NBUK], gpos[NBUK], cnt2[NBUK];
    int t = threadIdx.x;
    int s = blockIdx.x*CHUNK, e = min(s + CHUNK, EE);
    for (int i = t; i < NBUK; i += 256){ cnt[i] = 0; cnt2[i] = 0; }
    __syncthreads();
    for (int i = s + t; i < e; i += 256)
        atomicAdd(&cnt[((unsigned)ei[EE + i]) >> 7], 1u);
    __syncthreads();
    for (int i = t; i < NBUK; i += 256){
        unsigned c = cnt[i];
        gpos[i] = c ? atomicAdd(&cursor[i], c) : 0u;
    }
    __syncthreads();
    for (int i = s + t; i < e; i += 256){
        unsigned c = (unsigned)ei[EE + i];
        unsigned r = (unsigned)ei[i];
        unsigned b = c >> 7;
        unsigned rk = atomicAdd(&cnt2[b], 1u);
        packed[gpos[b] + rk] = ((c & 127u) << 24) | r;
    }
}

// ---------- per-bucket degree -> dinv (coalesced, no global atomics) ----------
__global__ void bdeg_kernel(const unsigned* __restrict__ packed, const unsigned* __restrict__ base,
                            float* __restrict__ dinv){
    __shared__ unsigned cnt[128];
    int t = threadIdx.x;
    if (t < 128) cnt[t] = 0;
    __syncthreads();
    unsigned s = base[blockIdx.x], e = base[blockIdx.x + 1];
    for (unsigned i = s + t; i < e; i += 256)
        atomicAdd(&cnt[packed[i] >> 24], 1u);
    __syncthreads();
    if (t < 128){
        int node = blockIdx.x*128 + t;
        if (node < NN) dinv[node] = cnt[t] ? rsqrtf((float)cnt[t]) : 0.f;
    }
}

// ---------- GEMM: h2 = dinv[row] * perm/sign( x @ W^T ) in bf16 ----------
__launch_bounds__(256, 2)
__global__ void gemm_kernel(const float* __restrict__ x, const float* __restrict__ w,
                            const float* __restrict__ dinv,
                            unsigned short* __restrict__ h2, int Nn){
    __shared__ unsigned short bfrag[8*8*64*8];   // 64 KB
    int tid = threadIdx.x;
    for (int idx = tid; idx < 8*8*64*8; idx += 256){
        int r = idx & 7, l = (idx >> 3) & 63, t = (idx >> 9) & 7, s = idx >> 12;
        int n = t*16 + (l & 15);
        int k = s*32 + ((l >> 4) << 3) + r;
        bfrag[idx] = f2bf(w[n*INC + k]);
    }
    __syncthreads();

    int wave = tid >> 6, lane = tid & 63;
    int mrow = blockIdx.x*64 + wave*16 + (lane & 15);
    const float* xr = x + (size_t)min(mrow, Nn-1) * INC;
    int kg = (lane >> 4) << 3;   // 0,8,16,24

    f32x4 acc[8];
    #pragma unroll
    for (int t = 0; t < 8; ++t) acc[t] = (f32x4){0.f,0.f,0.f,0.f};

    #pragma unroll
    for (int s = 0; s < 8; ++s){
        const float4* p = (const float4*)(xr + s*32 + kg);
        float4 a0 = p[0], a1 = p[1];
        bf16x8 af;
        af[0]=f2bf(a0.x); af[1]=f2bf(a0.y); af[2]=f2bf(a0.z); af[3]=f2bf(a0.w);
        af[4]=f2bf(a1.x); af[5]=f2bf(a1.y); af[6]=f2bf(a1.z); af[7]=f2bf(a1.w);
        #pragma unroll
        for (int t = 0; t < 8; ++t){
            const bf16x8 bf = *(const bf16x8*)&bfrag[((s*8 + t)*64 + lane)*8];
            acc[t] = __builtin_amdgcn_mfma_f32_16x16x32_bf16(af, bf, acc[t], 0, 0, 0);
        }
    }

    int rbase = blockIdx.x*64 + wave*16 + ((lane >> 4) << 2);
    float sc[4];
    #pragma unroll
    for (int r = 0; r < 4; ++r){
        int row = rbase + r;
        sc[r] = (row < Nn) ? dinv[row] : 0.f;
    }
    #pragma unroll
    for (int t = 0; t < 8; ++t){
        int o  = t*16 + (lane & 15);          // original output channel
        int dc = (o + 64) & 127;              // rolled destination column
        float sgn = (o < 64) ? 1.f : -1.f;    // negate-second-half folded through roll
        #pragma unroll
        for (int r = 0; r < 4; ++r){
            int row = rbase + r;
            if (row < Nn) h2[(size_t)row*OUTC + dc] = f2bf(sgn * sc[r] * acc[t][r]);
        }
    }
}

// ---------- accumulate: one block per bucket, fp32 LDS accumulators ----------
__launch_bounds__(512)
__global__ void accum_kernel(const unsigned short* __restrict__ h2,
                             const unsigned* __restrict__ packed,
                             const unsigned* __restrict__ base,
                             const float* __restrict__ dinv,
                             float* __restrict__ out){
    __shared__ float acc[128*128];    // 64 KB -> 2 blocks/CU
    float4 z = {0.f,0.f,0.f,0.f};
    for (int i = threadIdx.x; i < 4096; i += 512) *(float4*)&acc[i*4] = z;
    __syncthreads();

    unsigned s = base[blockIdx.x], e = base[blockIdx.x + 1];
    const unsigned* h2u = (const unsigned*)h2;
    unsigned lane = threadIdx.x & 63, wv = threadIdx.x >> 6;   // 8 waves
    unsigned c = lane*2;
    unsigned i = s + wv;
    for (; i + 25 <= e; i += 32){   // 4 edges per wave-iter, wave-stride 8
        unsigned u0 = packed[i], u1 = packed[i+8], u2 = packed[i+16], u3 = packed[i+24];
        unsigned v0 = h2u[(size_t)(u0 & 0xFFFFFFu)*64 + lane];
        unsigned v1 = h2u[(size_t)(u1 & 0xFFFFFFu)*64 + lane];
        unsigned v2 = h2u[(size_t)(u2 & 0xFFFFFFu)*64 + lane];
        unsigned v3 = h2u[(size_t)(u3 & 0xFFFFFFu)*64 + lane];
        atomicAdd(&acc[((u0 >> 24) << 7) + c],     bf2f(v0 & 0xFFFFu));
        atomicAdd(&acc[((u0 >> 24) << 7) + c + 1], bf2f(v0 >> 16));
        atomicAdd(&acc[((u1 >> 24) << 7) + c],     bf2f(v1 & 0xFFFFu));
        atomicAdd(&acc[((u1 >> 24) << 7) + c + 1], bf2f(v1 >> 16));
        atomicAdd(&acc[((u2 >> 24) << 7) + c],     bf2f(v2 & 0xFFFFu));
        atomicAdd(&acc[((u2 >> 24) << 7) + c + 1], bf2f(v2 >> 16));
        atomicAdd(&acc[((u3 >> 24) << 7) + c],     bf2f(v3 & 0xFFFFu));
        atomicAdd(&acc[((u3 >> 24) << 7) + c + 1], bf2f(v3 >> 16));
    }
    for (; i < e; i += 8){
        unsigned u = packed[i];
        unsigned v = h2u[(size_t)(u & 0xFFFFFFu)*64 + lane];
        atomicAdd(&acc[((u >> 24) << 7) + c],     bf2f(v & 0xFFFFu));
        atomicAdd(&acc[((u >> 24) << 7) + c + 1], bf2f(v >> 16));
    }
    __syncthreads();

    int nb = blockIdx.x * 128;
    for (int j = threadIdx.x; j < 4096; j += 512){
        int loc = j >> 5, q = j & 31;
        int node = nb + loc;
        if (node < NN){
            float sc = dinv[node];
            float4 v = *(float4*)&acc[(loc << 7) + (q << 2)];
            v.x *= sc; v.y *= sc; v.z *= sc; v.w *= sc;
            *(float4*)(out + (size_t)node*OUTC + (q << 2)) = v;
        }
    }
}

extern "C" void kernel_launch(void* const* d_in, const int* in_sizes, int n_in,
                              void* d_out, int out_size, void* d_ws, size_t ws_size,
                              hipStream_t stream){
    const float* x  = (const float*)d_in[0];
    const int*   ei = (const int*)d_in[1];      // [2][E]: row then col
    const float* w  = (const float*)d_in[2];    // [128][256]
    float* out = (float*)d_out;

    char* ws = (char*)d_ws;
    size_t off = 0;
    auto alloc = [&](size_t b) -> char* {
        char* p = ws + off;
        off += (b + 255) & ~(size_t)255;
        return p;
    };
    unsigned* bcnt   = (unsigned*)alloc((size_t)NBUK*4);
    unsigned* base   = (unsigned*)alloc((size_t)(NBUK+1)*4);
    unsigned* cursor = (unsigned*)alloc((size_t)NBUK*4);
    float*    dinv   = (float*)  alloc((size_t)NN*4);
    unsigned* packed = (unsigned*)alloc((size_t)EE*4);
    unsigned short* h2 = (unsigned short*)alloc((size_t)NN*OUTC*2);

    hipMemsetAsync(bcnt, 0, (size_t)NBUK*4, stream);
    hist_kernel<<<256, 256, 0, stream>>>(ei + EE, bcnt);
    scanb_kernel<<<1, 1024, 0, stream>>>(bcnt, base, cursor);
    partition_kernel<<<NPB, 256, 0, stream>>>(ei, cursor, packed);
    bdeg_kernel<<<NBUK, 256, 0, stream>>>(packed, base, dinv);
    gemm_kernel<<<(NN+63)/64, 256, 0, stream>>>(x, w, dinv, h2, NN);
    accum_kernel<<<NBUK, 512, 0, stream>>>(h2, packed, base, dinv, out);
}

// Round 4
// 225.648 us; speedup vs baseline: 6.5357x; 6.5357x over previous
//
#include <hip/hip_runtime.h>
#include <hip/hip_bf16.h>

#define NN 100000
#define EE 1600000
#define INC 256
#define OUTC 128
#define NBUK 782            // ceil(100000 / 128) node buckets
#define NPB  256            // partition blocks
#define CHUNK ((EE + NPB - 1) / NPB)   // 6250 edges per partition block

typedef short bf16x8 __attribute__((ext_vector_type(8)));
typedef float f32x4 __attribute__((ext_vector_type(4)));

static __device__ __forceinline__ unsigned short f2bf(float f){
    unsigned u = __builtin_bit_cast(unsigned, f);
    u += 0x7fffu + ((u >> 16) & 1u);
    return (unsigned short)(u >> 16);
}
static __device__ __forceinline__ float bf2f(unsigned short h){
    unsigned u = ((unsigned)h) << 16;
    return __builtin_bit_cast(float, u);
}

// ---------- bucket histogram (LDS-aggregated) ----------
__global__ void hist_kernel(const int* __restrict__ col, unsigned* __restrict__ bcnt){
    __shared__ unsigned h[NBUK];
    for (int i = threadIdx.x; i < NBUK; i += 256) h[i] = 0;
    __syncthreads();
    for (int i = blockIdx.x*blockDim.x + threadIdx.x; i < EE; i += gridDim.x*blockDim.x)
        atomicAdd(&h[((unsigned)col[i]) >> 7], 1u);
    __syncthreads();
    for (int i = threadIdx.x; i < NBUK; i += 256)
        if (h[i]) atomicAdd(&bcnt[i], h[i]);
}

// ---------- scan of 782 bucket counts -> base, cursor ----------
__global__ void scanb_kernel(const unsigned* __restrict__ bcnt,
                             unsigned* __restrict__ base, unsigned* __restrict__ cursor){
    __shared__ unsigned tmp[1024];
    int t = threadIdx.x;
    unsigned v = (t < NBUK) ? bcnt[t] : 0u;
    tmp[t] = v;
    __syncthreads();
    for (int off = 1; off < 1024; off <<= 1){
        unsigned x = (t >= off) ? tmp[t-off] : 0u;
        __syncthreads();
        tmp[t] += x;
        __syncthreads();
    }
    if (t < NBUK){ unsigned ex = tmp[t] - v; base[t] = ex; cursor[t] = ex; }
    if (t == 0) base[NBUK] = EE;
}

// ---------- partition edges into bucket regions (block-batched reservations) ----------
__global__ void partition_kernel(const int* __restrict__ ei, unsigned* __restrict__ cursor,
                                 unsigned* __restrict__ packed){
    __shared__ unsigned cnt[NBUK], gpos[NBUK], cnt2[NBUK];
    int t = threadIdx.x;
    int s = blockIdx.x*CHUNK, e = min(s + CHUNK, EE);
    for (int i = t; i < NBUK; i += 256){ cnt[i] = 0; cnt2[i] = 0; }
    __syncthreads();
    for (int i = s + t; i < e; i += 256)
        atomicAdd(&cnt[((unsigned)ei[EE + i]) >> 7], 1u);
    __syncthreads();
    for (int i = t; i < NBUK; i += 256){
        unsigned c = cnt[i];
        gpos[i] = c ? atomicAdd(&cursor[i], c) : 0u;
    }
    __syncthreads();
    for (int i = s + t; i < e; i += 256){
        unsigned c = (unsigned)ei[EE + i];
        unsigned r = (unsigned)ei[i];
        unsigned b = c >> 7;
        unsigned rk = atomicAdd(&cnt2[b], 1u);
        packed[gpos[b] + rk] = ((c & 127u) << 24) | r;
    }
}

// ---------- per-bucket counting sort -> CSR (erow, noffs) + dinv ----------
__global__ void sort_kernel(const unsigned* __restrict__ packed, const unsigned* __restrict__ base,
                            unsigned* __restrict__ erow, unsigned* __restrict__ noffs,
                            float* __restrict__ dinv){
    __shared__ unsigned cnt[128], cur[128], tmp[128];
    int t = threadIdx.x;
    unsigned s = base[blockIdx.x], e = base[blockIdx.x + 1];
    if (t < 128) cnt[t] = 0;
    __syncthreads();
    for (unsigned i = s + t; i < e; i += 256)
        atomicAdd(&cnt[packed[i] >> 24], 1u);
    __syncthreads();
    if (t < 128) tmp[t] = cnt[t];
    __syncthreads();
    for (int off = 1; off < 128; off <<= 1){
        unsigned v = (t >= off && t < 128) ? tmp[t-off] : 0u;
        __syncthreads();
        if (t < 128) tmp[t] += v;
        __syncthreads();
    }
    if (t < 128){
        unsigned ex = s + tmp[t] - cnt[t];   // global CSR offset for this node
        cur[t] = ex;
        int node = blockIdx.x*128 + t;
        if (node < NN){
            noffs[node] = ex;
            dinv[node] = cnt[t] ? rsqrtf((float)cnt[t]) : 0.f;
        }
    }
    if (blockIdx.x == 0 && t == 0) noffs[NN] = EE;
    __syncthreads();
    for (unsigned i = s + t; i < e; i += 256){
        unsigned u = packed[i];
        unsigned pos = atomicAdd(&cur[u >> 24], 1u);
        erow[pos] = u & 0xFFFFFFu;
    }
}

// ---------- GEMM: h2 = dinv[row] * perm/sign( x @ W^T ) in bf16 ----------
__launch_bounds__(256, 2)
__global__ void gemm_kernel(const float* __restrict__ x, const float* __restrict__ w,
                            const float* __restrict__ dinv,
                            unsigned short* __restrict__ h2, int Nn){
    __shared__ unsigned short bfrag[8*8*64*8];   // 64 KB
    int tid = threadIdx.x;
    for (int idx = tid; idx < 8*8*64*8; idx += 256){
        int r = idx & 7, l = (idx >> 3) & 63, t = (idx >> 9) & 7, s = idx >> 12;
        int n = t*16 + (l & 15);
        int k = s*32 + ((l >> 4) << 3) + r;
        bfrag[idx] = f2bf(w[n*INC + k]);
    }
    __syncthreads();

    int wave = tid >> 6, lane = tid & 63;
    int mrow = blockIdx.x*64 + wave*16 + (lane & 15);
    const float* xr = x + (size_t)min(mrow, Nn-1) * INC;
    int kg = (lane >> 4) << 3;   // 0,8,16,24

    f32x4 acc[8];
    #pragma unroll
    for (int t = 0; t < 8; ++t) acc[t] = (f32x4){0.f,0.f,0.f,0.f};

    #pragma unroll
    for (int s = 0; s < 8; ++s){
        const float4* p = (const float4*)(xr + s*32 + kg);
        float4 a0 = p[0], a1 = p[1];
        bf16x8 af;
        af[0]=f2bf(a0.x); af[1]=f2bf(a0.y); af[2]=f2bf(a0.z); af[3]=f2bf(a0.w);
        af[4]=f2bf(a1.x); af[5]=f2bf(a1.y); af[6]=f2bf(a1.z); af[7]=f2bf(a1.w);
        #pragma unroll
        for (int t = 0; t < 8; ++t){
            const bf16x8 bf = *(const bf16x8*)&bfrag[((s*8 + t)*64 + lane)*8];
            acc[t] = __builtin_amdgcn_mfma_f32_16x16x32_bf16(af, bf, acc[t], 0, 0, 0);
        }
    }

    int rbase = blockIdx.x*64 + wave*16 + ((lane >> 4) << 2);
    float sc[4];
    #pragma unroll
    for (int r = 0; r < 4; ++r){
        int row = rbase + r;
        sc[r] = (row < Nn) ? dinv[row] : 0.f;
    }
    #pragma unroll
    for (int t = 0; t < 8; ++t){
        int o  = t*16 + (lane & 15);          // original output channel
        int dc = (o + 64) & 127;              // rolled destination column
        float sgn = (o < 64) ? 1.f : -1.f;    // negate-second-half folded through roll
        #pragma unroll
        for (int r = 0; r < 4; ++r){
            int row = rbase + r;
            if (row < Nn) h2[(size_t)row*OUTC + dc] = f2bf(sgn * sc[r] * acc[t][r]);
        }
    }
}

// ---------- gather-aggregate: one wave per node, 4 edges in flight ----------
__launch_bounds__(256)
__global__ void gather_kernel(const unsigned short* __restrict__ h2,
                              const unsigned* __restrict__ noffs,
                              const unsigned* __restrict__ erow,
                              const float* __restrict__ dinv,
                              float* __restrict__ out, int Nn){
    int node = blockIdx.x*4 + (threadIdx.x >> 6);
    if (node >= Nn) return;
    int lane = threadIdx.x & 63;
    unsigned s = noffs[node], e = noffs[node+1];
    int half = lane >> 5;          // which edge of the pair
    int cb = (lane & 31) << 2;     // 4 columns per lane

    float a0=0.f, a1=0.f, a2=0.f, a3=0.f;
    float b0=0.f, b1=0.f, b2=0.f, b3=0.f;
    unsigned p = s;
    for (; p + 4 <= e; p += 4){
        unsigned r0 = erow[p + half];
        unsigned r1 = erow[p + 2 + half];
        ushort4 v0 = *(const ushort4*)(h2 + (size_t)r0*OUTC + cb);
        ushort4 v1 = *(const ushort4*)(h2 + (size_t)r1*OUTC + cb);
        a0 += bf2f(v0.x); a1 += bf2f(v0.y); a2 += bf2f(v0.z); a3 += bf2f(v0.w);
        b0 += bf2f(v1.x); b1 += bf2f(v1.y); b2 += bf2f(v1.z); b3 += bf2f(v1.w);
    }
    for (; p < e; p += 2){
        unsigned idx = p + half;
        if (idx < e){
            unsigned row = erow[idx];
            ushort4 v = *(const ushort4*)(h2 + (size_t)row*OUTC + cb);
            a0 += bf2f(v.x); a1 += bf2f(v.y); a2 += bf2f(v.z); a3 += bf2f(v.w);
        }
    }
    a0 += b0; a1 += b1; a2 += b2; a3 += b3;
    a0 += __shfl_down(a0, 32);
    a1 += __shfl_down(a1, 32);
    a2 += __shfl_down(a2, 32);
    a3 += __shfl_down(a3, 32);
    if (half == 0){
        float wc = dinv[node];
        float4 o = {a0*wc, a1*wc, a2*wc, a3*wc};
        *(float4*)(out + (size_t)node*OUTC + cb) = o;
    }
}

extern "C" void kernel_launch(void* const* d_in, const int* in_sizes, int n_in,
                              void* d_out, int out_size, void* d_ws, size_t ws_size,
                              hipStream_t stream){
    const float* x  = (const float*)d_in[0];
    const int*   ei = (const int*)d_in[1];      // [2][E]: row then col
    const float* w  = (const float*)d_in[2];    // [128][256]
    float* out = (float*)d_out;

    char* ws = (char*)d_ws;
    size_t off = 0;
    auto alloc = [&](size_t b) -> char* {
        char* p = ws + off;
        off += (b + 255) & ~(size_t)255;
        return p;
    };
    unsigned* bcnt   = (unsigned*)alloc((size_t)NBUK*4);
    unsigned* base   = (unsigned*)alloc((size_t)(NBUK+1)*4);
    unsigned* cursor = (unsigned*)alloc((size_t)NBUK*4);
    float*    dinv   = (float*)  alloc((size_t)NN*4);
    unsigned* packed = (unsigned*)alloc((size_t)EE*4);
    unsigned* erow   = (unsigned*)alloc((size_t)EE*4);
    unsigned* noffs  = (unsigned*)alloc((size_t)(NN+1)*4);
    unsigned short* h2 = (unsigned short*)alloc((size_t)NN*OUTC*2);

    hipMemsetAsync(bcnt, 0, (size_t)NBUK*4, stream);
    hist_kernel<<<256, 256, 0, stream>>>(ei + EE, bcnt);
    scanb_kernel<<<1, 1024, 0, stream>>>(bcnt, base, cursor);
    partition_kernel<<<NPB, 256, 0, stream>>>(ei, cursor, packed);
    sort_kernel<<<NBUK, 256, 0, stream>>>(packed, base, erow, noffs, dinv);
    gemm_kernel<<<(NN+63)/64, 256, 0, stream>>>(x, w, dinv, h2, NN);
    gather_kernel<<<(NN+3)/4, 256, 0, stream>>>(h2, noffs, erow, dinv, out, NN);
}

// Round 5
// 170.765 us; speedup vs baseline: 8.6363x; 1.3214x over previous
//
#include <hip/hip_runtime.h>
#include <hip/hip_bf16.h>

#define NN 100000
#define EE 1600000
#define INC 256
#define OUTC 128
#define NBUK 782            // ceil(100000 / 128) node buckets
#define NPB  256            // partition blocks
#define CHUNK ((EE + NPB - 1) / NPB)   // 6250 edges per partition block

typedef short bf16x8 __attribute__((ext_vector_type(8)));
typedef float f32x4 __attribute__((ext_vector_type(4)));

static __device__ __forceinline__ unsigned short f2bf(float f){
    unsigned u = __builtin_bit_cast(unsigned, f);
    u += 0x7fffu + ((u >> 16) & 1u);
    return (unsigned short)(u >> 16);
}
static __device__ __forceinline__ float bf2f(unsigned short h){
    unsigned u = ((unsigned)h) << 16;
    return __builtin_bit_cast(float, u);
}

// ---------- bucket histogram (LDS-aggregated) ----------
__global__ void hist_kernel(const int* __restrict__ col, unsigned* __restrict__ bcnt){
    __shared__ unsigned h[NBUK];
    for (int i = threadIdx.x; i < NBUK; i += 256) h[i] = 0;
    __syncthreads();
    for (int i = blockIdx.x*blockDim.x + threadIdx.x; i < EE; i += gridDim.x*blockDim.x)
        atomicAdd(&h[((unsigned)col[i]) >> 7], 1u);
    __syncthreads();
    for (int i = threadIdx.x; i < NBUK; i += 256)
        if (h[i]) atomicAdd(&bcnt[i], h[i]);
}

// ---------- scan of 782 bucket counts -> base, cursor ----------
__global__ void scanb_kernel(const unsigned* __restrict__ bcnt,
                             unsigned* __restrict__ base, unsigned* __restrict__ cursor){
    __shared__ unsigned tmp[1024];
    int t = threadIdx.x;
    unsigned v = (t < NBUK) ? bcnt[t] : 0u;
    tmp[t] = v;
    __syncthreads();
    for (int off = 1; off < 1024; off <<= 1){
        unsigned x = (t >= off) ? tmp[t-off] : 0u;
        __syncthreads();
        tmp[t] += x;
        __syncthreads();
    }
    if (t < NBUK){ unsigned ex = tmp[t] - v; base[t] = ex; cursor[t] = ex; }
    if (t == 0) base[NBUK] = EE;
}

// ---------- partition edges into bucket regions (block-batched reservations) ----------
__global__ void partition_kernel(const int* __restrict__ ei, unsigned* __restrict__ cursor,
                                 unsigned* __restrict__ packed){
    __shared__ unsigned cnt[NBUK], gpos[NBUK], cnt2[NBUK];
    int t = threadIdx.x;
    int s = blockIdx.x*CHUNK, e = min(s + CHUNK, EE);
    for (int i = t; i < NBUK; i += 256){ cnt[i] = 0; cnt2[i] = 0; }
    __syncthreads();
    for (int i = s + t; i < e; i += 256)
        atomicAdd(&cnt[((unsigned)ei[EE + i]) >> 7], 1u);
    __syncthreads();
    for (int i = t; i < NBUK; i += 256){
        unsigned c = cnt[i];
        gpos[i] = c ? atomicAdd(&cursor[i], c) : 0u;
    }
    __syncthreads();
    for (int i = s + t; i < e; i += 256){
        unsigned c = (unsigned)ei[EE + i];
        unsigned r = (unsigned)ei[i];
        unsigned b = c >> 7;
        unsigned rk = atomicAdd(&cnt2[b], 1u);
        packed[gpos[b] + rk] = ((c & 127u) << 24) | r;
    }
}

// ---------- per-bucket counting sort -> CSR (erow, noffs) + dinv ----------
__global__ void sort_kernel(const unsigned* __restrict__ packed, const unsigned* __restrict__ base,
                            unsigned* __restrict__ erow, unsigned* __restrict__ noffs,
                            float* __restrict__ dinv){
    __shared__ unsigned cnt[128], cur[128], tmp[128];
    int t = threadIdx.x;
    unsigned s = base[blockIdx.x], e = base[blockIdx.x + 1];
    if (t < 128) cnt[t] = 0;
    __syncthreads();
    for (unsigned i = s + t; i < e; i += 256)
        atomicAdd(&cnt[packed[i] >> 24], 1u);
    __syncthreads();
    if (t < 128) tmp[t] = cnt[t];
    __syncthreads();
    for (int off = 1; off < 128; off <<= 1){
        unsigned v = (t >= off && t < 128) ? tmp[t-off] : 0u;
        __syncthreads();
        if (t < 128) tmp[t] += v;
        __syncthreads();
    }
    if (t < 128){
        unsigned ex = s + tmp[t] - cnt[t];   // global CSR offset for this node
        cur[t] = ex;
        int node = blockIdx.x*128 + t;
        if (node < NN){
            noffs[node] = ex;
            dinv[node] = cnt[t] ? rsqrtf((float)cnt[t]) : 0.f;
        }
    }
    if (blockIdx.x == 0 && t == 0) noffs[NN] = EE;
    __syncthreads();
    for (unsigned i = s + t; i < e; i += 256){
        unsigned u = packed[i];
        unsigned pos = atomicAdd(&cur[u >> 24], 1u);
        erow[pos] = u & 0xFFFFFFu;
    }
}

// ---------- W -> fragment-ordered bf16 (one-time prep) ----------
__global__ void wprep_kernel(const float* __restrict__ w, unsigned short* __restrict__ wfrag){
    int idx = blockIdx.x*256 + threadIdx.x;
    if (idx < 8*8*64*8){
        int r = idx & 7, l = (idx >> 3) & 63, t = (idx >> 9) & 7, s = idx >> 12;
        int n = t*16 + (l & 15);
        int k = s*32 + ((l >> 4) << 3) + r;
        wfrag[idx] = f2bf(w[n*INC + k]);
    }
}

// ---------- GEMM: h2 = dinv[row] * perm/sign( x @ W^T ) in bf16, no LDS ----------
__launch_bounds__(256, 4)
__global__ void gemm_kernel(const float* __restrict__ x, const unsigned short* __restrict__ wfrag,
                            const float* __restrict__ dinv,
                            unsigned short* __restrict__ h2, int Nn){
    int tid = threadIdx.x;
    int wave = tid >> 6, lane = tid & 63;
    int mrow = blockIdx.x*64 + wave*16 + (lane & 15);
    const float* xr = x + (size_t)min(mrow, Nn-1) * INC;
    int kg = (lane >> 4) << 3;   // 0,8,16,24
    const bf16x8* wf = (const bf16x8*)wfrag;   // [(s*8+t)*64 + lane]

    f32x4 acc[8];
    #pragma unroll
    for (int t = 0; t < 8; ++t) acc[t] = (f32x4){0.f,0.f,0.f,0.f};

    #pragma unroll
    for (int s = 0; s < 8; ++s){
        const float4* p = (const float4*)(xr + s*32 + kg);
        float4 a0 = p[0], a1 = p[1];
        bf16x8 af;
        af[0]=f2bf(a0.x); af[1]=f2bf(a0.y); af[2]=f2bf(a0.z); af[3]=f2bf(a0.w);
        af[4]=f2bf(a1.x); af[5]=f2bf(a1.y); af[6]=f2bf(a1.z); af[7]=f2bf(a1.w);
        #pragma unroll
        for (int t = 0; t < 8; ++t){
            bf16x8 bf = wf[(s*8 + t)*64 + lane];
            acc[t] = __builtin_amdgcn_mfma_f32_16x16x32_bf16(af, bf, acc[t], 0, 0, 0);
        }
    }

    int rbase = blockIdx.x*64 + wave*16 + ((lane >> 4) << 2);
    float sc[4];
    #pragma unroll
    for (int r = 0; r < 4; ++r){
        int row = rbase + r;
        sc[r] = (row < Nn) ? dinv[row] : 0.f;
    }
    #pragma unroll
    for (int t = 0; t < 8; ++t){
        int o  = t*16 + (lane & 15);          // original output channel
        int dc = (o + 64) & 127;              // rolled destination column
        float sgn = (o < 64) ? 1.f : -1.f;    // negate-second-half folded through roll
        #pragma unroll
        for (int r = 0; r < 4; ++r){
            int row = rbase + r;
            if (row < Nn) h2[(size_t)row*OUTC + dc] = f2bf(sgn * sc[r] * acc[t][r]);
        }
    }
}

// ---------- gather-aggregate: one wave per node, 4 edges in flight ----------
__launch_bounds__(256)
__global__ void gather_kernel(const unsigned short* __restrict__ h2,
                              const unsigned* __restrict__ noffs,
                              const unsigned* __restrict__ erow,
                              const float* __restrict__ dinv,
                              float* __restrict__ out, int Nn){
    int node = blockIdx.x*4 + (threadIdx.x >> 6);
    if (node >= Nn) return;
    int lane = threadIdx.x & 63;
    unsigned s = noffs[node], e = noffs[node+1];
    int half = lane >> 5;          // which edge of the pair
    int cb = (lane & 31) << 2;     // 4 columns per lane

    float a0=0.f, a1=0.f, a2=0.f, a3=0.f;
    float b0=0.f, b1=0.f, b2=0.f, b3=0.f;
    unsigned p = s;
    for (; p + 4 <= e; p += 4){
        unsigned r0 = erow[p + half];
        unsigned r1 = erow[p + 2 + half];
        ushort4 v0 = *(const ushort4*)(h2 + (size_t)r0*OUTC + cb);
        ushort4 v1 = *(const ushort4*)(h2 + (size_t)r1*OUTC + cb);
        a0 += bf2f(v0.x); a1 += bf2f(v0.y); a2 += bf2f(v0.z); a3 += bf2f(v0.w);
        b0 += bf2f(v1.x); b1 += bf2f(v1.y); b2 += bf2f(v1.z); b3 += bf2f(v1.w);
    }
    for (; p < e; p += 2){
        unsigned idx = p + half;
        if (idx < e){
            unsigned row = erow[idx];
            ushort4 v = *(const ushort4*)(h2 + (size_t)row*OUTC + cb);
            a0 += bf2f(v.x); a1 += bf2f(v.y); a2 += bf2f(v.z); a3 += bf2f(v.w);
        }
    }
    a0 += b0; a1 += b1; a2 += b2; a3 += b3;
    a0 += __shfl_down(a0, 32);
    a1 += __shfl_down(a1, 32);
    a2 += __shfl_down(a2, 32);
    a3 += __shfl_down(a3, 32);
    if (half == 0){
        float wc = dinv[node];
        float4 o = {a0*wc, a1*wc, a2*wc, a3*wc};
        *(float4*)(out + (size_t)node*OUTC + cb) = o;
    }
}

extern "C" void kernel_launch(void* const* d_in, const int* in_sizes, int n_in,
                              void* d_out, int out_size, void* d_ws, size_t ws_size,
                              hipStream_t stream){
    const float* x  = (const float*)d_in[0];
    const int*   ei = (const int*)d_in[1];      // [2][E]: row then col
    const float* w  = (const float*)d_in[2];    // [128][256]
    float* out = (float*)d_out;

    char* ws = (char*)d_ws;
    size_t off = 0;
    auto alloc = [&](size_t b) -> char* {
        char* p = ws + off;
        off += (b + 255) & ~(size_t)255;
        return p;
    };
    unsigned* bcnt   = (unsigned*)alloc((size_t)NBUK*4);
    unsigned* base   = (unsigned*)alloc((size_t)(NBUK+1)*4);
    unsigned* cursor = (unsigned*)alloc((size_t)NBUK*4);
    float*    dinv   = (float*)  alloc((size_t)NN*4);
    unsigned* packed = (unsigned*)alloc((size_t)EE*4);
    unsigned* erow   = (unsigned*)alloc((size_t)EE*4);
    unsigned* noffs  = (unsigned*)alloc((size_t)(NN+1)*4);
    unsigned short* wfrag = (unsigned short*)alloc((size_t)8*8*64*8*2);
    unsigned short* h2 = (unsigned short*)alloc((size_t)NN*OUTC*2);

    hipMemsetAsync(bcnt, 0, (size_t)NBUK*4, stream);
    wprep_kernel<<<128, 256, 0, stream>>>(w, wfrag);
    hist_kernel<<<256, 256, 0, stream>>>(ei + EE, bcnt);
    scanb_kernel<<<1, 1024, 0, stream>>>(bcnt, base, cursor);
    partition_kernel<<<NPB, 256, 0, stream>>>(ei, cursor, packed);
    sort_kernel<<<NBUK, 256, 0, stream>>>(packed, base, erow, noffs, dinv);
    gemm_kernel<<<(NN+63)/64, 256, 0, stream>>>(x, wfrag, dinv, h2, NN);
    gather_kernel<<<(NN+3)/4, 256, 0, stream>>>(h2, noffs, erow, dinv, out, NN);
}

// Round 6
// 162.493 us; speedup vs baseline: 9.0759x; 1.0509x over previous
//
#include <hip/hip_runtime.h>
#include <hip/hip_bf16.h>

#define NN 100000
#define EE 1600000
#define INC 256
#define OUTC 128
#define NBUK 782            // ceil(100000 / 128) node buckets
#define NPB  256            // partition blocks
#define CHUNK ((EE + NPB - 1) / NPB)   // 6250 edges per partition block

typedef short bf16x8 __attribute__((ext_vector_type(8)));
typedef float f32x4 __attribute__((ext_vector_type(4)));

static __device__ __forceinline__ unsigned short f2bf(float f){
    unsigned u = __builtin_bit_cast(unsigned, f);
    u += 0x7fffu + ((u >> 16) & 1u);
    return (unsigned short)(u >> 16);
}
static __device__ __forceinline__ float bf2f(unsigned short h){
    unsigned u = ((unsigned)h) << 16;
    return __builtin_bit_cast(float, u);
}

// ---------- bucket histogram (LDS-aggregated) ----------
__global__ void hist_kernel(const int* __restrict__ col, unsigned* __restrict__ bcnt){
    __shared__ unsigned h[NBUK];
    for (int i = threadIdx.x; i < NBUK; i += 256) h[i] = 0;
    __syncthreads();
    for (int i = blockIdx.x*blockDim.x + threadIdx.x; i < EE; i += gridDim.x*blockDim.x)
        atomicAdd(&h[((unsigned)col[i]) >> 7], 1u);
    __syncthreads();
    for (int i = threadIdx.x; i < NBUK; i += 256)
        if (h[i]) atomicAdd(&bcnt[i], h[i]);
}

// ---------- scan of 782 bucket counts -> base, cursor ----------
__global__ void scanb_kernel(const unsigned* __restrict__ bcnt,
                             unsigned* __restrict__ base, unsigned* __restrict__ cursor){
    __shared__ unsigned tmp[1024];
    int t = threadIdx.x;
    unsigned v = (t < NBUK) ? bcnt[t] : 0u;
    tmp[t] = v;
    __syncthreads();
    for (int off = 1; off < 1024; off <<= 1){
        unsigned x = (t >= off) ? tmp[t-off] : 0u;
        __syncthreads();
        tmp[t] += x;
        __syncthreads();
    }
    if (t < NBUK){ unsigned ex = tmp[t] - v; base[t] = ex; cursor[t] = ex; }
    if (t == 0) base[NBUK] = EE;
}

// ---------- partition edges into bucket regions (block-batched reservations) ----------
__global__ void partition_kernel(const int* __restrict__ ei, unsigned* __restrict__ cursor,
                                 unsigned* __restrict__ packed){
    __shared__ unsigned cnt[NBUK], gpos[NBUK], cnt2[NBUK];
    int t = threadIdx.x;
    int s = blockIdx.x*CHUNK, e = min(s + CHUNK, EE);
    for (int i = t; i < NBUK; i += 256){ cnt[i] = 0; cnt2[i] = 0; }
    __syncthreads();
    for (int i = s + t; i < e; i += 256)
        atomicAdd(&cnt[((unsigned)ei[EE + i]) >> 7], 1u);
    __syncthreads();
    for (int i = t; i < NBUK; i += 256){
        unsigned c = cnt[i];
        gpos[i] = c ? atomicAdd(&cursor[i], c) : 0u;
    }
    __syncthreads();
    for (int i = s + t; i < e; i += 256){
        unsigned c = (unsigned)ei[EE + i];
        unsigned r = (unsigned)ei[i];
        unsigned b = c >> 7;
        unsigned rk = atomicAdd(&cnt2[b], 1u);
        packed[gpos[b] + rk] = ((c & 127u) << 24) | r;
    }
}

// ---------- per-bucket counting sort -> CSR (erow, noffs) + dinv ----------
__global__ void sort_kernel(const unsigned* __restrict__ packed, const unsigned* __restrict__ base,
                            unsigned* __restrict__ erow, unsigned* __restrict__ noffs,
                            float* __restrict__ dinv){
    __shared__ unsigned cnt[128], cur[128], tmp[128];
    int t = threadIdx.x;
    unsigned s = base[blockIdx.x], e = base[blockIdx.x + 1];
    if (t < 128) cnt[t] = 0;
    __syncthreads();
    for (unsigned i = s + t; i < e; i += 256)
        atomicAdd(&cnt[packed[i] >> 24], 1u);
    __syncthreads();
    if (t < 128) tmp[t] = cnt[t];
    __syncthreads();
    for (int off = 1; off < 128; off <<= 1){
        unsigned v = (t >= off && t < 128) ? tmp[t-off] : 0u;
        __syncthreads();
        if (t < 128) tmp[t] += v;
        __syncthreads();
    }
    if (t < 128){
        unsigned ex = s + tmp[t] - cnt[t];   // global CSR offset for this node
        cur[t] = ex;
        int node = blockIdx.x*128 + t;
        if (node < NN){
            noffs[node] = ex;
            dinv[node] = cnt[t] ? rsqrtf((float)cnt[t]) : 0.f;
        }
    }
    if (blockIdx.x == 0 && t == 0) noffs[NN] = EE;
    __syncthreads();
    for (unsigned i = s + t; i < e; i += 256){
        unsigned u = packed[i];
        unsigned pos = atomicAdd(&cur[u >> 24], 1u);
        erow[pos] = u & 0xFFFFFFu;
    }
}

// ---------- W -> fragment-ordered bf16 (one-time prep) ----------
__global__ void wprep_kernel(const float* __restrict__ w, unsigned short* __restrict__ wfrag){
    int idx = blockIdx.x*256 + threadIdx.x;
    if (idx < 8*8*64*8){
        int r = idx & 7, l = (idx >> 3) & 63, t = (idx >> 9) & 7, s = idx >> 12;
        int n = t*16 + (l & 15);
        int k = s*32 + ((l >> 4) << 3) + r;
        wfrag[idx] = f2bf(w[n*INC + k]);
    }
}

// ---------- GEMM: h2 = dinv[row] * perm/sign( x @ W^T ) in bf16, no LDS ----------
__launch_bounds__(256, 4)
__global__ void gemm_kernel(const float* __restrict__ x, const unsigned short* __restrict__ wfrag,
                            const float* __restrict__ dinv,
                            unsigned short* __restrict__ h2, int Nn){
    int tid = threadIdx.x;
    int wave = tid >> 6, lane = tid & 63;
    int mrow = blockIdx.x*64 + wave*16 + (lane & 15);
    const float* xr = x + (size_t)min(mrow, Nn-1) * INC;
    int kg = (lane >> 4) << 3;   // 0,8,16,24
    const bf16x8* wf = (const bf16x8*)wfrag;   // [(s*8+t)*64 + lane]

    f32x4 acc[8];
    #pragma unroll
    for (int t = 0; t < 8; ++t) acc[t] = (f32x4){0.f,0.f,0.f,0.f};

    #pragma unroll
    for (int s = 0; s < 8; ++s){
        const float4* p = (const float4*)(xr + s*32 + kg);
        float4 a0 = p[0], a1 = p[1];
        bf16x8 af;
        af[0]=f2bf(a0.x); af[1]=f2bf(a0.y); af[2]=f2bf(a0.z); af[3]=f2bf(a0.w);
        af[4]=f2bf(a1.x); af[5]=f2bf(a1.y); af[6]=f2bf(a1.z); af[7]=f2bf(a1.w);
        #pragma unroll
        for (int t = 0; t < 8; ++t){
            bf16x8 bf = wf[(s*8 + t)*64 + lane];
            acc[t] = __builtin_amdgcn_mfma_f32_16x16x32_bf16(af, bf, acc[t], 0, 0, 0);
        }
    }

    int rbase = blockIdx.x*64 + wave*16 + ((lane >> 4) << 2);
    float sc[4];
    #pragma unroll
    for (int r = 0; r < 4; ++r){
        int row = rbase + r;
        sc[r] = (row < Nn) ? dinv[row] : 0.f;
    }
    #pragma unroll
    for (int t = 0; t < 8; ++t){
        int o  = t*16 + (lane & 15);          // original output channel
        int dc = (o + 64) & 127;              // rolled destination column
        float sgn = (o < 64) ? 1.f : -1.f;    // negate-second-half folded through roll
        #pragma unroll
        for (int r = 0; r < 4; ++r){
            int row = rbase + r;
            if (row < Nn) h2[(size_t)row*OUTC + dc] = f2bf(sgn * sc[r] * acc[t][r]);
        }
    }
}

// ---------- gather-aggregate: wave per node, lane = col-pair, 8 edges in flight ----------
__launch_bounds__(256)
__global__ void gather_kernel(const unsigned short* __restrict__ h2,
                              const unsigned* __restrict__ noffs,
                              const unsigned* __restrict__ erow,
                              const float* __restrict__ dinv,
                              float* __restrict__ out, int Nn){
    int node = blockIdx.x*4 + (threadIdx.x >> 6);
    if (node >= Nn) return;
    int lane = threadIdx.x & 63;
    unsigned s = noffs[node], e = noffs[node+1];
    unsigned deg = e - s;
    const unsigned* h2u = (const unsigned*)h2;   // row = 64 u32 (2 bf16 each)

    float lA0=0,lA1=0,lA2=0,lA3=0,lA4=0,lA5=0,lA6=0,lA7=0;
    float hA0=0,hA1=0,hA2=0,hA3=0,hA4=0,hA5=0,hA6=0,hA7=0;

    for (unsigned b = 0; b < deg; b += 64){
        unsigned my = b + lane;
        unsigned eidx = (my < deg) ? erow[s + my] : 0u;
        unsigned chunk = min(64u, deg - b);
        unsigned j = 0;
        for (; j + 8 <= chunk; j += 8){
            unsigned r0 = __shfl(eidx, (int)(j+0));
            unsigned r1 = __shfl(eidx, (int)(j+1));
            unsigned r2 = __shfl(eidx, (int)(j+2));
            unsigned r3 = __shfl(eidx, (int)(j+3));
            unsigned r4 = __shfl(eidx, (int)(j+4));
            unsigned r5 = __shfl(eidx, (int)(j+5));
            unsigned r6 = __shfl(eidx, (int)(j+6));
            unsigned r7 = __shfl(eidx, (int)(j+7));
            unsigned v0 = h2u[(size_t)r0*64 + lane];
            unsigned v1 = h2u[(size_t)r1*64 + lane];
            unsigned v2 = h2u[(size_t)r2*64 + lane];
            unsigned v3 = h2u[(size_t)r3*64 + lane];
            unsigned v4 = h2u[(size_t)r4*64 + lane];
            unsigned v5 = h2u[(size_t)r5*64 + lane];
            unsigned v6 = h2u[(size_t)r6*64 + lane];
            unsigned v7 = h2u[(size_t)r7*64 + lane];
            lA0 += bf2f((unsigned short)(v0 & 0xFFFFu)); hA0 += bf2f((unsigned short)(v0 >> 16));
            lA1 += bf2f((unsigned short)(v1 & 0xFFFFu)); hA1 += bf2f((unsigned short)(v1 >> 16));
            lA2 += bf2f((unsigned short)(v2 & 0xFFFFu)); hA2 += bf2f((unsigned short)(v2 >> 16));
            lA3 += bf2f((unsigned short)(v3 & 0xFFFFu)); hA3 += bf2f((unsigned short)(v3 >> 16));
            lA4 += bf2f((unsigned short)(v4 & 0xFFFFu)); hA4 += bf2f((unsigned short)(v4 >> 16));
            lA5 += bf2f((unsigned short)(v5 & 0xFFFFu)); hA5 += bf2f((unsigned short)(v5 >> 16));
            lA6 += bf2f((unsigned short)(v6 & 0xFFFFu)); hA6 += bf2f((unsigned short)(v6 >> 16));
            lA7 += bf2f((unsigned short)(v7 & 0xFFFFu)); hA7 += bf2f((unsigned short)(v7 >> 16));
        }
        for (; j < chunk; ++j){
            unsigned r = __shfl(eidx, (int)j);
            unsigned v = h2u[(size_t)r*64 + lane];
            lA0 += bf2f((unsigned short)(v & 0xFFFFu));
            hA0 += bf2f((unsigned short)(v >> 16));
        }
    }
    float lo = ((lA0+lA1)+(lA2+lA3)) + ((lA4+lA5)+(lA6+lA7));
    float hi = ((hA0+hA1)+(hA2+hA3)) + ((hA4+hA5)+(hA6+hA7));
    float wc = dinv[node];
    float2 o = {lo*wc, hi*wc};
    *(float2*)(out + (size_t)node*OUTC + lane*2) = o;
}

extern "C" void kernel_launch(void* const* d_in, const int* in_sizes, int n_in,
                              void* d_out, int out_size, void* d_ws, size_t ws_size,
                              hipStream_t stream){
    const float* x  = (const float*)d_in[0];
    const int*   ei = (const int*)d_in[1];      // [2][E]: row then col
    const float* w  = (const float*)d_in[2];    // [128][256]
    float* out = (float*)d_out;

    char* ws = (char*)d_ws;
    size_t off = 0;
    auto alloc = [&](size_t b) -> char* {
        char* p = ws + off;
        off += (b + 255) & ~(size_t)255;
        return p;
    };
    unsigned* bcnt   = (unsigned*)alloc((size_t)NBUK*4);
    unsigned* base   = (unsigned*)alloc((size_t)(NBUK+1)*4);
    unsigned* cursor = (unsigned*)alloc((size_t)NBUK*4);
    float*    dinv   = (float*)  alloc((size_t)NN*4);
    unsigned* packed = (unsigned*)alloc((size_t)EE*4);
    unsigned* erow   = (unsigned*)alloc((size_t)EE*4);
    unsigned* noffs  = (unsigned*)alloc((size_t)(NN+1)*4);
    unsigned short* wfrag = (unsigned short*)alloc((size_t)8*8*64*8*2);
    unsigned short* h2 = (unsigned short*)alloc((size_t)NN*OUTC*2);

    hipMemsetAsync(bcnt, 0, (size_t)NBUK*4, stream);
    wprep_kernel<<<128, 256, 0, stream>>>(w, wfrag);
    hist_kernel<<<256, 256, 0, stream>>>(ei + EE, bcnt);
    scanb_kernel<<<1, 1024, 0, stream>>>(bcnt, base, cursor);
    partition_kernel<<<NPB, 256, 0, stream>>>(ei, cursor, packed);
    sort_kernel<<<NBUK, 256, 0, stream>>>(packed, base, erow, noffs, dinv);
    gemm_kernel<<<(NN+63)/64, 256, 0, stream>>>(x, wfrag, dinv, h2, NN);
    gather_kernel<<<(NN+3)/4, 256, 0, stream>>>(h2, noffs, erow, dinv, out, NN);
}